// Round 17
// baseline (162.458 us; speedup 1.0000x reference)
//
#include <hip/hip_runtime.h>
#include <hip/hip_fp16.h>

#define B_HIST 512   // blocks in hist/scatter phases (must match both)
#define SHIFT  9     // coarse bucket = dst >> 9 (512 nodes/bucket); NB <= 256 for N <= 131072

typedef _Float16 f16x8 __attribute__((ext_vector_type(8)));
typedef float f32x4 __attribute__((ext_vector_type(4)));
typedef float f32x2 __attribute__((ext_vector_type(2)));

#define FP8_SCALE 32.0f
#define FP8_INV   (1.0f / 32.0f)

// ================= CSR build: two-level counting sort, LDS atomics only =================

__global__ __launch_bounds__(256) void p1_hist(const int* __restrict__ dst,
                                               int* __restrict__ histT, int E) {
  __shared__ int h[256];
  const int t = threadIdx.x;
  h[t] = 0;
  __syncthreads();
  const int epb = (E + B_HIST - 1) / B_HIST;
  const int beg = blockIdx.x * epb;
  const int end = min(beg + epb, E);
  for (int e = beg + t; e < end; e += 256)
    atomicAdd(&h[dst[e] >> SHIFT], 1);          // LDS atomic
  __syncthreads();
  histT[t * B_HIST + blockIdx.x] = h[t];
}

__global__ __launch_bounds__(256) void p2a_colscan(int* __restrict__ histT,
                                                   int* __restrict__ bsum) {
  __shared__ int sdata[256];
  const int bin = blockIdx.x, t = threadIdx.x;
  const int i0 = bin * B_HIST + 2 * t;
  int c0 = histT[i0], c1 = histT[i0 + 1];
  int s = c0 + c1;
  sdata[t] = s;
  __syncthreads();
  for (int off = 1; off < 256; off <<= 1) {
    int x = 0;
    if (t >= off) x = sdata[t - off];
    __syncthreads();
    if (t >= off) sdata[t] += x;
    __syncthreads();
  }
  int excl = sdata[t] - s;
  histT[i0] = excl;
  histT[i0 + 1] = excl + c0;
  if (t == 255) bsum[bin] = sdata[255];
}

__global__ __launch_bounds__(256) void p2b_scan(const int* __restrict__ bsum,
                                                int* __restrict__ colstart) {
  __shared__ int sdata[256];
  const int t = threadIdx.x;
  int v = bsum[t];
  sdata[t] = v;
  __syncthreads();
  for (int off = 1; off < 256; off <<= 1) {
    int x = 0;
    if (t >= off) x = sdata[t - off];
    __syncthreads();
    if (t >= off) sdata[t] += x;
    __syncthreads();
  }
  colstart[t] = sdata[t] - v;
  if (t == 255) colstart[256] = sdata[255];
}

__global__ __launch_bounds__(256) void p3_scatter(const int* __restrict__ src,
                                                  const int* __restrict__ dst,
                                                  const int* __restrict__ histT,
                                                  const int* __restrict__ colstart,
                                                  int* __restrict__ pbuf, int E) {
  __shared__ int cur[256];
  const int t = threadIdx.x;
  cur[t] = colstart[t] + histT[t * B_HIST + blockIdx.x];
  __syncthreads();
  const int epb = (E + B_HIST - 1) / B_HIST;
  const int beg = blockIdx.x * epb;
  const int end = min(beg + epb, E);
  for (int e = beg + t; e < end; e += 256) {
    int d = dst[e];
    int s = src[e];
    int pos = atomicAdd(&cur[d >> SHIFT], 1);   // LDS atomic
    pbuf[pos] = ((d & 511) << 17) | s;
  }
}

// P4: per-bucket fine counting sort -> rowptr, dinv, ssrc
__global__ __launch_bounds__(256) void p4_fine(const int* __restrict__ pbuf,
                                               const int* __restrict__ colstart,
                                               int* __restrict__ rowptr,
                                               float* __restrict__ dinv,
                                               int* __restrict__ ssrc, int N, int NB) {
  __shared__ int cnt[512];
  __shared__ int sdata[256];
  __shared__ int cur[512];
  const int b = blockIdx.x, t = threadIdx.x;
  const int base = colstart[b], endp = colstart[b + 1];
  cnt[2 * t] = 0; cnt[2 * t + 1] = 0;
  __syncthreads();
  for (int i = base + t; i < endp; i += 256)
    atomicAdd(&cnt[pbuf[i] >> 17], 1);
  __syncthreads();
  int c0 = cnt[2 * t], c1 = cnt[2 * t + 1];
  int s = c0 + c1;
  sdata[t] = s;
  __syncthreads();
  for (int off = 1; off < 256; off <<= 1) {
    int x = 0;
    if (t >= off) x = sdata[t - off];
    __syncthreads();
    if (t >= off) sdata[t] += x;
    __syncthreads();
  }
  int excl = sdata[t] - s;
  int e0 = base + excl, e1 = base + excl + c0;
  cur[2 * t] = e0;
  cur[2 * t + 1] = e1;
  int node0 = (b << SHIFT) + 2 * t;
  if (node0 < N) {
    rowptr[node0] = e0;
    dinv[node0] = rsqrtf((float)c0 + 1.0f);
  }
  if (node0 + 1 < N) {
    rowptr[node0 + 1] = e1;
    dinv[node0 + 1] = rsqrtf((float)c1 + 1.0f);
  }
  if (b == NB - 1 && t == 0) rowptr[N] = endp;
  __syncthreads();
  for (int i = base + t; i < endp; i += 256) {
    int p = pbuf[i];
    int pos = atomicAdd(&cur[p >> 17], 1);      // LDS atomic
    ssrc[pos] = p & 0x1FFFF;
  }
}

// ============ W pre-pack: fp32 W[K][COLS] -> fp16 B-fragments ((kq)*COLS+col)*8+j ============

template <int COLS, int K>
__global__ __launch_bounds__(256) void wpack_kernel(const float* __restrict__ W,
                                                    _Float16* __restrict__ P) {
  int task = blockIdx.x * 256 + threadIdx.x;
  if (task >= (K / 8) * COLS) return;
  int col = task % COLS;
  int kq = task / COLS;
  _Float16 tmp[8];
#pragma unroll
  for (int j = 0; j < 8; ++j)
    tmp[j] = (_Float16)W[(kq * 8 + j) * COLS + col];
  *reinterpret_cast<f16x8*>(&P[task * 8]) = *reinterpret_cast<const f16x8*>(tmp);
}

// ========== MFMA GEMM: O (*dinv) = X[N][K] @ Wpacked ==========
// FP8_OUT: O = fp8 e4m3 bytes, col-blocked [2][N][32] (scaled FP8_SCALE).
// else:    O = fp16, col-blocked [COLS/16][N][16].

template <int COLS, int K, typename XT, bool FP8_OUT>
__global__ __launch_bounds__(256) void mfma_gemm(const XT* __restrict__ X,
                                                 const _Float16* __restrict__ wpk,
                                                 const float* __restrict__ dinv,
                                                 void* __restrict__ O, int N) {
  constexpr int NKK = K / 32;        // MFMA K-steps
  constexpr int NCT = COLS / 16;     // col tiles
  constexpr int RCH = K / 8;         // 16B fp16 chunks per row
  constexpr int SWM = RCH - 1;       // chunk swizzle mask
  __shared__ _Float16 xs[64 * K];
  __shared__ _Float16 wb[K * COLS];  // packed B-frags (copied from wpk)
  const int t = threadIdx.x;
  const int row0 = blockIdx.x * 64;

  for (int i = t; i < K * COLS / 8; i += 256)
    *reinterpret_cast<f16x8*>(&wb[i * 8]) = reinterpret_cast<const f16x8*>(wpk)[i];
  for (int task = t; task < 64 * RCH; task += 256) {
    int row = task / RCH, c = task % RCH;
    int grow = row0 + row;
    f16x8 hv;
#pragma unroll
    for (int j = 0; j < 8; ++j) hv[j] = (_Float16)0.f;
    if (grow < N) {
      if constexpr (sizeof(XT) == 4) {
        const float4* xr = reinterpret_cast<const float4*>(X + (size_t)grow * K);
        float4 v0 = xr[c * 2], v1 = xr[c * 2 + 1];
        hv[0] = (_Float16)v0.x; hv[1] = (_Float16)v0.y;
        hv[2] = (_Float16)v0.z; hv[3] = (_Float16)v0.w;
        hv[4] = (_Float16)v1.x; hv[5] = (_Float16)v1.y;
        hv[6] = (_Float16)v1.z; hv[7] = (_Float16)v1.w;
      } else {
        hv = reinterpret_cast<const f16x8*>(X + (size_t)grow * K)[c];
      }
    }
    int sc = c ^ (row & SWM);
    *reinterpret_cast<f16x8*>(&xs[row * K + sc * 8]) = hv;
  }
  __syncthreads();

  const int wave = t >> 6, lane = t & 63;
  const int q = lane >> 4, c = lane & 15;
  const int wrow = wave * 16;

  f16x8 bfrag[NKK][NCT];
#pragma unroll
  for (int kk = 0; kk < NKK; ++kk)
#pragma unroll
    for (int ct = 0; ct < NCT; ++ct)
      bfrag[kk][ct] = *reinterpret_cast<const f16x8*>(
          &wb[(size_t)((kk * 4 + q) * COLS + ct * 16 + c) * 8]);

  f32x4 acc[NCT];
#pragma unroll
  for (int ct = 0; ct < NCT; ++ct) acc[ct] = {0.f, 0.f, 0.f, 0.f};

#pragma unroll
  for (int kk = 0; kk < NKK; ++kk) {
    int row = wrow + c;
    int cc = (kk * 4 + q) ^ (row & SWM);
    f16x8 afrag = *reinterpret_cast<const f16x8*>(&xs[row * K + cc * 8]);
#pragma unroll
    for (int ct = 0; ct < NCT; ++ct)
      acc[ct] = __builtin_amdgcn_mfma_f32_16x16x32_f16(afrag, bfrag[kk][ct], acc[ct], 0, 0, 0);
  }

#pragma unroll
  for (int r = 0; r < 4; ++r) {
    int row = row0 + wrow + q * 4 + r;
    if (row < N) {
      float di = dinv[row];
#pragma unroll
      for (int ct = 0; ct < NCT; ++ct) {
        int col = ct * 16 + c;
        if constexpr (FP8_OUT) {
          float v = acc[ct][r] * di * FP8_SCALE;
          int pk = __builtin_amdgcn_cvt_pk_fp8_f32(v, v, 0, false);
          ((unsigned char*)O)[(size_t)(col >> 5) * N * 32 + (size_t)row * 32 + (col & 31)] =
              (unsigned char)(pk & 0xFF);
        } else {
          ((__half*)O)[(size_t)(col >> 4) * N * 16 + (size_t)row * 16 + (col & 15)] =
              __float2half(acc[ct][r] * di);
        }
      }
    }
  }
}

// ====== layer-1 gather pass: fp8 half-table [N][32B] (3.2MB, L2-resident) ======
// 8 lanes/node; lane = 4 fp8 cols (uint). Window 16 edges (2 coalesced ssrc loads
// + shfl broadcast); 16 row loads in flight per group; 8 chains/wave.
__global__ __launch_bounds__(256) void gather64p_kernel(const int* __restrict__ rowptr,
                                                        const int* __restrict__ ssrc,
                                                        const float* __restrict__ dinv,
                                                        const unsigned int* __restrict__ gh,
                                                        const float* __restrict__ bias32,
                                                        __half* __restrict__ outb,
                                                        int colbase, int N) {
  int node = (blockIdx.x * 256 + threadIdx.x) >> 3;
  int col = threadIdx.x & 7;
  if (node >= N) return;
  int beg = rowptr[node], end = rowptr[node + 1];
  float4 aa0 = {0.f, 0.f, 0.f, 0.f}, aa1 = aa0, aa2 = aa0, aa3 = aa0;
  for (int base = beg; base < end; base += 16) {
    int m = end - base;
    int sv0 = 0, sv1 = 0;
    if (col < m) sv0 = ssrc[base + col];
    if (col + 8 < m) sv1 = ssrc[base + 8 + col];
    unsigned int v[16];
#pragma unroll
    for (int u = 0; u < 8; ++u)
      if (u < m) v[u] = gh[(size_t)__shfl(sv0, u, 8) * 8 + col];
#pragma unroll
    for (int u = 8; u < 16; ++u)
      if (u < m) v[u] = gh[(size_t)__shfl(sv1, u - 8, 8) * 8 + col];
#pragma unroll
    for (int u = 0; u < 16; ++u) {
      if (u < m) {
        f32x2 lo = __builtin_amdgcn_cvt_pk_f32_fp8((int)v[u], false);
        f32x2 hi = __builtin_amdgcn_cvt_pk_f32_fp8((int)v[u], true);
        if ((u & 3) == 0) { aa0.x += lo.x; aa0.y += lo.y; aa0.z += hi.x; aa0.w += hi.y; }
        if ((u & 3) == 1) { aa1.x += lo.x; aa1.y += lo.y; aa1.z += hi.x; aa1.w += hi.y; }
        if ((u & 3) == 2) { aa2.x += lo.x; aa2.y += lo.y; aa2.z += hi.x; aa2.w += hi.y; }
        if ((u & 3) == 3) { aa3.x += lo.x; aa3.y += lo.y; aa3.z += hi.x; aa3.w += hi.y; }
      }
    }
  }
  unsigned int vs = gh[(size_t)node * 8 + col];
  f32x2 slo = __builtin_amdgcn_cvt_pk_f32_fp8((int)vs, false);
  f32x2 shi = __builtin_amdgcn_cvt_pk_f32_fp8((int)vs, true);
  float inv = dinv[node] * FP8_INV;
  float4 bb = *reinterpret_cast<const float4*>(bias32 + 4 * col);
  float ox = fmaxf(fmaf(inv, (aa0.x + aa1.x) + (aa2.x + aa3.x) + slo.x, bb.x), 0.f);
  float oy = fmaxf(fmaf(inv, (aa0.y + aa1.y) + (aa2.y + aa3.y) + slo.y, bb.y), 0.f);
  float oz = fmaxf(fmaf(inv, (aa0.z + aa1.z) + (aa2.z + aa3.z) + shi.x, bb.z), 0.f);
  float ow = fmaxf(fmaf(inv, (aa0.w + aa1.w) + (aa2.w + aa3.w) + shi.y, bb.w), 0.f);
  union { __half2 h2[2]; uint2 u; } cv;
  cv.h2[0] = __floats2half2_rn(ox, oy);
  cv.h2[1] = __floats2half2_rn(oz, ow);
  *reinterpret_cast<uint2*>(outb + (size_t)node * 64 + colbase + 4 * col) = cv.u;
}

// ====== layer-2 gather pass: fp16 half-table [N][16] (3.2MB) ======
// 8 lanes/node; lane = 2 fp16 cols (uint). Window 16. Output fp32 (final).
__global__ __launch_bounds__(256) void gather32p_kernel(const int* __restrict__ rowptr,
                                                        const int* __restrict__ ssrc,
                                                        const float* __restrict__ dinv,
                                                        const unsigned int* __restrict__ gh,
                                                        const float* __restrict__ bias16,
                                                        float* __restrict__ outb,
                                                        int colbase, int N) {
  int node = (blockIdx.x * 256 + threadIdx.x) >> 3;
  int col = threadIdx.x & 7;
  if (node >= N) return;
  int beg = rowptr[node], end = rowptr[node + 1];
  float2 aa0 = {0.f, 0.f}, aa1 = aa0, aa2 = aa0, aa3 = aa0;
  for (int base = beg; base < end; base += 16) {
    int m = end - base;
    int sv0 = 0, sv1 = 0;
    if (col < m) sv0 = ssrc[base + col];
    if (col + 8 < m) sv1 = ssrc[base + 8 + col];
    unsigned int v[16];
#pragma unroll
    for (int u = 0; u < 8; ++u)
      if (u < m) v[u] = gh[(size_t)__shfl(sv0, u, 8) * 8 + col];
#pragma unroll
    for (int u = 8; u < 16; ++u)
      if (u < m) v[u] = gh[(size_t)__shfl(sv1, u - 8, 8) * 8 + col];
#pragma unroll
    for (int u = 0; u < 16; ++u) {
      if (u < m) {
        float2 f = __half22float2(*(__half2*)&v[u]);
        if ((u & 3) == 0) { aa0.x += f.x; aa0.y += f.y; }
        if ((u & 3) == 1) { aa1.x += f.x; aa1.y += f.y; }
        if ((u & 3) == 2) { aa2.x += f.x; aa2.y += f.y; }
        if ((u & 3) == 3) { aa3.x += f.x; aa3.y += f.y; }
      }
    }
  }
  unsigned int vs = gh[(size_t)node * 8 + col];
  float2 gs = __half22float2(*(__half2*)&vs);
  float di = dinv[node];
  float2 bb = *reinterpret_cast<const float2*>(bias16 + 2 * col);
  float2 o;
  o.x = fmaf(di, (aa0.x + aa1.x) + (aa2.x + aa3.x) + gs.x, bb.x);
  o.y = fmaf(di, (aa0.y + aa1.y) + (aa2.y + aa3.y) + gs.y, bb.y);
  *reinterpret_cast<float2*>(outb + (size_t)node * 32 + colbase + 2 * col) = o;
}

// ================= launch =================

extern "C" void kernel_launch(void* const* d_in, const int* in_sizes, int n_in,
                              void* d_out, int out_size, void* d_ws, size_t ws_size,
                              hipStream_t stream) {
  const float* x  = (const float*)d_in[0];
  const int*   ei = (const int*)d_in[1];
  const float* W1 = (const float*)d_in[2];
  const float* b1 = (const float*)d_in[3];
  const float* W2 = (const float*)d_in[4];
  const float* b2 = (const float*)d_in[5];
  float* out = (float*)d_out;

  const int H = in_sizes[3];            // 64
  const int F = in_sizes[2] / H;        // 128
  const int N = in_sizes[0] / F;        // 100000
  const int E = in_sizes[1] / 2;        // 1600000
  const int* src = ei;
  const int* dst = ei + E;
  const int NB = (N + 511) >> SHIFT;    // coarse buckets (196 for N=100k)

  char* w = (char*)d_ws;
  auto alloc = [&](size_t bytes) { char* p = w; w += (bytes + 255) & ~(size_t)255; return p; };
  int*           histT    = (int*)alloc((size_t)256 * B_HIST * 4);
  int*           bsum     = (int*)alloc(256 * 4);
  int*           colstart = (int*)alloc(257 * 4);
  int*           pbuf     = (int*)alloc((size_t)E * 4);
  int*           ssrc     = (int*)alloc((size_t)E * 4);
  int*           rowptr   = (int*)alloc((size_t)(N + 1) * 4);
  float*         dinv     = (float*)alloc((size_t)N * 4);
  _Float16*      wp1      = (_Float16*)alloc((size_t)128 * 64 * 2);
  _Float16*      wp2      = (_Float16*)alloc((size_t)64 * 32 * 2);
  unsigned char* g1q      = (unsigned char*)alloc((size_t)N * 64);      // [2][N][32] fp8
  __half*        buf1     = (__half*)alloc((size_t)N * 64 * 2);         // [N][64] fp16
  __half*        g2       = (__half*)alloc((size_t)N * 32 * 2);         // [2][N][16] fp16

  // W pre-pack (tiny, independent)
  wpack_kernel<64, 128><<<4, 256, 0, stream>>>(W1, wp1);
  wpack_kernel<32, 64><<<1, 256, 0, stream>>>(W2, wp2);

  // CSR build (no global atomics)
  p1_hist<<<B_HIST, 256, 0, stream>>>(dst, histT, E);
  p2a_colscan<<<256, 256, 0, stream>>>(histT, bsum);
  p2b_scan<<<1, 256, 0, stream>>>(bsum, colstart);
  p3_scatter<<<B_HIST, 256, 0, stream>>>(src, dst, histT, colstart, pbuf, E);
  p4_fine<<<NB, 256, 0, stream>>>(pbuf, colstart, rowptr, dinv, ssrc, N, NB);

  const int gblocks = (N * 8 + 255) / 256;

  // layer 1: g1q = fp8(S * dinv .* (x @ W1)), col-blocked halves
  mfma_gemm<64, 128, float, true><<<(N + 63) / 64, 256, 0, stream>>>(x, wp1, dinv, g1q, N);
  for (int q = 0; q < 2; ++q)
    gather64p_kernel<<<gblocks, 256, 0, stream>>>(rowptr, ssrc, dinv,
        (const unsigned int*)(g1q + (size_t)q * N * 32), b1 + 32 * q, buf1, 32 * q, N);

  // layer 2: g2 = dinv .* (r1 @ W2), col-blocked fp16 halves
  mfma_gemm<32, 64, _Float16, false><<<(N + 63) / 64, 256, 0, stream>>>(
      (const _Float16*)buf1, wp2, dinv, g2, N);
  for (int q = 0; q < 2; ++q)
    gather32p_kernel<<<gblocks, 256, 0, stream>>>(rowptr, ssrc, dinv,
        (const unsigned int*)g2 + (size_t)q * N * 8, b2 + 16 * q, out, 16 * q, N);
}

// Round 18
// 140.571 us; speedup vs baseline: 1.1557x; 1.1557x over previous
//
#include <hip/hip_runtime.h>
#include <hip/hip_fp16.h>

#define B_HIST 512   // blocks in hist/scatter phases (must match both)
#define SHIFT  9     // coarse bucket = dst >> 9 (512 nodes/bucket); NB <= 256 for N <= 131072

typedef _Float16 f16x8 __attribute__((ext_vector_type(8)));
typedef float f32x4 __attribute__((ext_vector_type(4)));

// ================= CSR build: two-level counting sort, LDS atomics only =================

__global__ __launch_bounds__(256) void p1_hist(const int* __restrict__ dst,
                                               int* __restrict__ histT, int E) {
  __shared__ int h[256];
  const int t = threadIdx.x;
  h[t] = 0;
  __syncthreads();
  const int epb = (E + B_HIST - 1) / B_HIST;
  const int beg = blockIdx.x * epb;
  const int end = min(beg + epb, E);
  for (int e = beg + t; e < end; e += 256)
    atomicAdd(&h[dst[e] >> SHIFT], 1);          // LDS atomic
  __syncthreads();
  histT[t * B_HIST + blockIdx.x] = h[t];
}

__global__ __launch_bounds__(256) void p2a_colscan(int* __restrict__ histT,
                                                   int* __restrict__ bsum) {
  __shared__ int sdata[256];
  const int bin = blockIdx.x, t = threadIdx.x;
  const int i0 = bin * B_HIST + 2 * t;
  int c0 = histT[i0], c1 = histT[i0 + 1];
  int s = c0 + c1;
  sdata[t] = s;
  __syncthreads();
  for (int off = 1; off < 256; off <<= 1) {
    int x = 0;
    if (t >= off) x = sdata[t - off];
    __syncthreads();
    if (t >= off) sdata[t] += x;
    __syncthreads();
  }
  int excl = sdata[t] - s;
  histT[i0] = excl;
  histT[i0 + 1] = excl + c0;
  if (t == 255) bsum[bin] = sdata[255];
}

__global__ __launch_bounds__(256) void p2b_scan(const int* __restrict__ bsum,
                                                int* __restrict__ colstart) {
  __shared__ int sdata[256];
  const int t = threadIdx.x;
  int v = bsum[t];
  sdata[t] = v;
  __syncthreads();
  for (int off = 1; off < 256; off <<= 1) {
    int x = 0;
    if (t >= off) x = sdata[t - off];
    __syncthreads();
    if (t >= off) sdata[t] += x;
    __syncthreads();
  }
  colstart[t] = sdata[t] - v;
  if (t == 255) colstart[256] = sdata[255];
}

__global__ __launch_bounds__(256) void p3_scatter(const int* __restrict__ src,
                                                  const int* __restrict__ dst,
                                                  const int* __restrict__ histT,
                                                  const int* __restrict__ colstart,
                                                  int* __restrict__ pbuf, int E) {
  __shared__ int cur[256];
  const int t = threadIdx.x;
  cur[t] = colstart[t] + histT[t * B_HIST + blockIdx.x];
  __syncthreads();
  const int epb = (E + B_HIST - 1) / B_HIST;
  const int beg = blockIdx.x * epb;
  const int end = min(beg + epb, E);
  for (int e = beg + t; e < end; e += 256) {
    int d = dst[e];
    int s = src[e];
    int pos = atomicAdd(&cur[d >> SHIFT], 1);   // LDS atomic
    pbuf[pos] = ((d & 511) << 17) | s;
  }
}

__global__ __launch_bounds__(256) void p4_fine(const int* __restrict__ pbuf,
                                               const int* __restrict__ colstart,
                                               int* __restrict__ rowptr,
                                               float* __restrict__ dinv,
                                               int* __restrict__ ssrc, int N, int NB) {
  __shared__ int cnt[512];
  __shared__ int sdata[256];
  __shared__ int cur[512];
  const int b = blockIdx.x, t = threadIdx.x;
  const int base = colstart[b], endp = colstart[b + 1];
  cnt[2 * t] = 0; cnt[2 * t + 1] = 0;
  __syncthreads();
  for (int i = base + t; i < endp; i += 256)
    atomicAdd(&cnt[pbuf[i] >> 17], 1);
  __syncthreads();
  int c0 = cnt[2 * t], c1 = cnt[2 * t + 1];
  int s = c0 + c1;
  sdata[t] = s;
  __syncthreads();
  for (int off = 1; off < 256; off <<= 1) {
    int x = 0;
    if (t >= off) x = sdata[t - off];
    __syncthreads();
    if (t >= off) sdata[t] += x;
    __syncthreads();
  }
  int excl = sdata[t] - s;
  int e0 = base + excl, e1 = base + excl + c0;
  cur[2 * t] = e0;
  cur[2 * t + 1] = e1;
  int node0 = (b << SHIFT) + 2 * t;
  if (node0 < N) {
    rowptr[node0] = e0;
    dinv[node0] = rsqrtf((float)c0 + 1.0f);
  }
  if (node0 + 1 < N) {
    rowptr[node0 + 1] = e1;
    dinv[node0 + 1] = rsqrtf((float)c1 + 1.0f);
  }
  if (b == NB - 1 && t == 0) rowptr[N] = endp;
  __syncthreads();
  for (int i = base + t; i < endp; i += 256) {
    int p = pbuf[i];
    int pos = atomicAdd(&cur[p >> 17], 1);      // LDS atomic
    ssrc[pos] = p & 0x1FFFF;
  }
}

// ========== MFMA GEMM: O[N][COLS] (fp16, *dinv) = X[N][K] @ W[K][COLS]fp32 ==========
// XT = float (layer 1) or _Float16 (layer 2). 4 waves, 64 rows/block.
// A-frag: row=lane&15, k=(lane>>4)*8+j. B-frag: col=lane&15, same k.
// C/D: col=lane&15, row=(lane>>4)*4+r (guide-verified).

template <int COLS, int K, typename XT>
__global__ __launch_bounds__(256) void mfma_gemm(const XT* __restrict__ X,
                                                 const float* __restrict__ W,
                                                 const float* __restrict__ dinv,
                                                 __half* __restrict__ O, int N) {
  constexpr int NKK = K / 32;        // MFMA K-steps
  constexpr int NCT = COLS / 16;     // col tiles
  constexpr int RCH = K / 8;         // 16B fp16 chunks per row
  constexpr int SWM = RCH - 1;       // chunk swizzle mask
  __shared__ _Float16 xs[64 * K];
  __shared__ _Float16 wb[K * COLS];  // packed B-frags: ((kk*4+q)*COLS + col)*8 + j
  const int t = threadIdx.x;
  const int row0 = blockIdx.x * 64;

  // pack W fragments (tiny, L2-resident)
  for (int task = t; task < NKK * 4 * COLS; task += 256) {
    int col = task % COLS;
    int kq = task / COLS;            // kk*4+q
    _Float16 tmp[8];
#pragma unroll
    for (int j = 0; j < 8; ++j)
      tmp[j] = (_Float16)W[(kq * 8 + j) * COLS + col];
    *reinterpret_cast<f16x8*>(&wb[task * 8]) = *reinterpret_cast<const f16x8*>(tmp);
  }
  // stage X tile as fp16, chunk-XOR-swizzled
  for (int task = t; task < 64 * RCH; task += 256) {
    int row = task / RCH, c = task % RCH;
    int grow = row0 + row;
    f16x8 hv;
#pragma unroll
    for (int j = 0; j < 8; ++j) hv[j] = (_Float16)0.f;
    if (grow < N) {
      if constexpr (sizeof(XT) == 4) {
        const float4* xr = reinterpret_cast<const float4*>(X + (size_t)grow * K);
        float4 v0 = xr[c * 2], v1 = xr[c * 2 + 1];
        hv[0] = (_Float16)v0.x; hv[1] = (_Float16)v0.y;
        hv[2] = (_Float16)v0.z; hv[3] = (_Float16)v0.w;
        hv[4] = (_Float16)v1.x; hv[5] = (_Float16)v1.y;
        hv[6] = (_Float16)v1.z; hv[7] = (_Float16)v1.w;
      } else {
        hv = reinterpret_cast<const f16x8*>(X + (size_t)grow * K)[c];
      }
    }
    int sc = c ^ (row & SWM);
    *reinterpret_cast<f16x8*>(&xs[row * K + sc * 8]) = hv;
  }
  __syncthreads();

  const int wave = t >> 6, lane = t & 63;
  const int q = lane >> 4, c = lane & 15;
  const int wrow = wave * 16;

  // preload all B fragments to registers
  f16x8 bfrag[NKK][NCT];
#pragma unroll
  for (int kk = 0; kk < NKK; ++kk)
#pragma unroll
    for (int ct = 0; ct < NCT; ++ct)
      bfrag[kk][ct] = *reinterpret_cast<const f16x8*>(
          &wb[(size_t)((kk * 4 + q) * COLS + ct * 16 + c) * 8]);

  f32x4 acc[NCT];
#pragma unroll
  for (int ct = 0; ct < NCT; ++ct) acc[ct] = {0.f, 0.f, 0.f, 0.f};

#pragma unroll
  for (int kk = 0; kk < NKK; ++kk) {
    int row = wrow + c;              // A row (block-local)
    int cc = (kk * 4 + q) ^ (row & SWM);
    f16x8 afrag = *reinterpret_cast<const f16x8*>(&xs[row * K + cc * 8]);
#pragma unroll
    for (int ct = 0; ct < NCT; ++ct)
      acc[ct] = __builtin_amdgcn_mfma_f32_16x16x32_f16(afrag, bfrag[kk][ct], acc[ct], 0, 0, 0);
  }

#pragma unroll
  for (int r = 0; r < 4; ++r) {
    int row = row0 + wrow + q * 4 + r;
    if (row < N) {
      float di = dinv[row];
#pragma unroll
      for (int ct = 0; ct < NCT; ++ct)
        O[(size_t)row * COLS + ct * 16 + c] = __float2half(acc[ct][r] * di);
    }
  }
}

// ================= CSR gather aggregation (fused epilogue) =================
// Sub-group per node; lane owns fixed columns (uint2 = 4 halves).
// Edge indices preloaded coalesced (one load per 16/8-edge window), broadcast
// via __shfl -> row loads issue immediately, up to 16 in flight per group.

// FDIM=64: 16 lanes/node. Output fp16 (relu'd), row = 16 uint2.
__global__ __launch_bounds__(256) void gather64_kernel(const int* __restrict__ rowptr,
                                                       const int* __restrict__ ssrc,
                                                       const float* __restrict__ dinv,
                                                       const uint2* __restrict__ g,
                                                       const float4* __restrict__ bias,
                                                       __half* __restrict__ outb, int N) {
  int node = (blockIdx.x * 256 + threadIdx.x) >> 4;
  int col = threadIdx.x & 15;
  if (node >= N) return;
  int beg = rowptr[node], end = rowptr[node + 1];
  float4 aa0 = {0.f, 0.f, 0.f, 0.f}, aa1 = aa0, aa2 = aa0, aa3 = aa0;
  for (int base = beg; base < end; base += 16) {
    int m = end - base;              // edges this window (clamped by u<m below)
    int sv = 0;
    if (col < m) sv = ssrc[base + col];          // coalesced: 16 consecutive indices
    uint2 v[16];
#pragma unroll
    for (int u = 0; u < 16; ++u) {
      if (u < m) {
        int s = __shfl(sv, u, 16);
        v[u] = g[(size_t)s * 16 + col];
      }
    }
#pragma unroll
    for (int u = 0; u < 16; ++u) {
      if (u < m) {
        float2 f0 = __half22float2(*(__half2*)&v[u].x);
        float2 f1 = __half22float2(*(__half2*)&v[u].y);
        if ((u & 3) == 0) { aa0.x += f0.x; aa0.y += f0.y; aa0.z += f1.x; aa0.w += f1.y; }
        if ((u & 3) == 1) { aa1.x += f0.x; aa1.y += f0.y; aa1.z += f1.x; aa1.w += f1.y; }
        if ((u & 3) == 2) { aa2.x += f0.x; aa2.y += f0.y; aa2.z += f1.x; aa2.w += f1.y; }
        if ((u & 3) == 3) { aa3.x += f0.x; aa3.y += f0.y; aa3.z += f1.x; aa3.w += f1.y; }
      }
    }
  }
  uint2 vs = g[(size_t)node * 16 + col];
  float2 g01 = __half22float2(*(__half2*)&vs.x);
  float2 g23 = __half22float2(*(__half2*)&vs.y);
  float di = dinv[node];
  float4 bb = bias[col];
  float ox = fmaxf(fmaf(di, (aa0.x + aa1.x) + (aa2.x + aa3.x) + g01.x, bb.x), 0.f);
  float oy = fmaxf(fmaf(di, (aa0.y + aa1.y) + (aa2.y + aa3.y) + g01.y, bb.y), 0.f);
  float oz = fmaxf(fmaf(di, (aa0.z + aa1.z) + (aa2.z + aa3.z) + g23.x, bb.z), 0.f);
  float ow = fmaxf(fmaf(di, (aa0.w + aa1.w) + (aa2.w + aa3.w) + g23.y, bb.w), 0.f);
  union { __half2 h2[2]; uint2 u; } cv;
  cv.h2[0] = __floats2half2_rn(ox, oy);
  cv.h2[1] = __floats2half2_rn(oz, ow);
  reinterpret_cast<uint2*>(outb)[(size_t)node * 16 + col] = cv.u;
}

// FDIM=32: 8 lanes/node. Output fp32 (final).
__global__ __launch_bounds__(256) void gather32_kernel(const int* __restrict__ rowptr,
                                                       const int* __restrict__ ssrc,
                                                       const float* __restrict__ dinv,
                                                       const uint2* __restrict__ g,
                                                       const float4* __restrict__ bias,
                                                       float4* __restrict__ outb, int N) {
  int node = (blockIdx.x * 256 + threadIdx.x) >> 3;
  int col = threadIdx.x & 7;
  if (node >= N) return;
  int beg = rowptr[node], end = rowptr[node + 1];
  float4 aa0 = {0.f, 0.f, 0.f, 0.f}, aa1 = aa0, aa2 = aa0, aa3 = aa0;
  for (int base = beg; base < end; base += 8) {
    int m = end - base;
    int sv = 0;
    if (col < m) sv = ssrc[base + col];          // coalesced: 8 consecutive indices
    uint2 v[8];
#pragma unroll
    for (int u = 0; u < 8; ++u) {
      if (u < m) {
        int s = __shfl(sv, u, 8);
        v[u] = g[(size_t)s * 8 + col];
      }
    }
#pragma unroll
    for (int u = 0; u < 8; ++u) {
      if (u < m) {
        float2 f0 = __half22float2(*(__half2*)&v[u].x);
        float2 f1 = __half22float2(*(__half2*)&v[u].y);
        if ((u & 3) == 0) { aa0.x += f0.x; aa0.y += f0.y; aa0.z += f1.x; aa0.w += f1.y; }
        if ((u & 3) == 1) { aa1.x += f0.x; aa1.y += f0.y; aa1.z += f1.x; aa1.w += f1.y; }
        if ((u & 3) == 2) { aa2.x += f0.x; aa2.y += f0.y; aa2.z += f1.x; aa2.w += f1.y; }
        if ((u & 3) == 3) { aa3.x += f0.x; aa3.y += f0.y; aa3.z += f1.x; aa3.w += f1.y; }
      }
    }
  }
  uint2 vs = g[(size_t)node * 8 + col];
  float2 g01 = __half22float2(*(__half2*)&vs.x);
  float2 g23 = __half22float2(*(__half2*)&vs.y);
  float di = dinv[node];
  float4 bb = bias[col];
  float4 o;
  o.x = fmaf(di, (aa0.x + aa1.x) + (aa2.x + aa3.x) + g01.x, bb.x);
  o.y = fmaf(di, (aa0.y + aa1.y) + (aa2.y + aa3.y) + g01.y, bb.y);
  o.z = fmaf(di, (aa0.z + aa1.z) + (aa2.z + aa3.z) + g23.x, bb.z);
  o.w = fmaf(di, (aa0.w + aa1.w) + (aa2.w + aa3.w) + g23.y, bb.w);
  outb[(size_t)node * 8 + col] = o;
}

// ================= launch =================

extern "C" void kernel_launch(void* const* d_in, const int* in_sizes, int n_in,
                              void* d_out, int out_size, void* d_ws, size_t ws_size,
                              hipStream_t stream) {
  const float* x  = (const float*)d_in[0];
  const int*   ei = (const int*)d_in[1];
  const float* W1 = (const float*)d_in[2];
  const float* b1 = (const float*)d_in[3];
  const float* W2 = (const float*)d_in[4];
  const float* b2 = (const float*)d_in[5];
  float* out = (float*)d_out;

  const int H = in_sizes[3];            // 64
  const int F = in_sizes[2] / H;        // 128
  const int N = in_sizes[0] / F;        // 100000
  const int E = in_sizes[1] / 2;        // 1600000
  const int* src = ei;
  const int* dst = ei + E;
  const int NB = (N + 511) >> SHIFT;    // coarse buckets (196 for N=100k)

  char* w = (char*)d_ws;
  auto alloc = [&](size_t bytes) { char* p = w; w += (bytes + 255) & ~(size_t)255; return p; };
  int*     histT    = (int*)alloc((size_t)256 * B_HIST * 4);
  int*     bsum     = (int*)alloc(256 * 4);
  int*     colstart = (int*)alloc(257 * 4);
  int*     pbuf     = (int*)alloc((size_t)E * 4);
  int*     ssrc     = (int*)alloc((size_t)E * 4);
  int*     rowptr   = (int*)alloc((size_t)(N + 1) * 4);
  float*   dinv     = (float*)alloc((size_t)N * 4);
  __half*  g1       = (__half*)alloc((size_t)N * 64 * 2);
  __half*  buf1     = (__half*)alloc((size_t)N * 64 * 2);  // relu output, fp16
  __half*  g2       = (__half*)alloc((size_t)N * 32 * 2);

  // CSR build (no global atomics)
  p1_hist<<<B_HIST, 256, 0, stream>>>(dst, histT, E);
  p2a_colscan<<<256, 256, 0, stream>>>(histT, bsum);
  p2b_scan<<<1, 256, 0, stream>>>(bsum, colstart);
  p3_scatter<<<B_HIST, 256, 0, stream>>>(src, dst, histT, colstart, pbuf, E);
  p4_fine<<<NB, 256, 0, stream>>>(pbuf, colstart, rowptr, dinv, ssrc, N, NB);

  // layer 1: g1 = dinv .* (x @ W1)   (fp16, MFMA)
  mfma_gemm<64, 128, float><<<(N + 63) / 64, 256, 0, stream>>>(x, W1, dinv, g1, N);
  gather64_kernel<<<(N * 16 + 255) / 256, 256, 0, stream>>>(rowptr, ssrc, dinv,
      (const uint2*)g1, (const float4*)b1, buf1, N);

  // layer 2: g2 = dinv .* (r1 @ W2)  (fp16, MFMA, fp16 input)
  mfma_gemm<32, 64, _Float16><<<(N + 63) / 64, 256, 0, stream>>>(
      (const _Float16*)buf1, W2, dinv, g2, N);
  gather32_kernel<<<(N * 8 + 255) / 256, 256, 0, stream>>>(rowptr, ssrc, dinv,
      (const uint2*)g2, (const float4*)b2, (float4*)out, N);
}